// Round 2
// baseline (230.958 us; speedup 1.0000x reference)
//
#include <hip/hip_runtime.h>
#include <hip/hip_bf16.h>
#include <stdint.h>

#define TOK   256
#define NOBJ  64
#define NDEMO 16
#define BATCH 256
#define SEQ   1105              /* 1 + 16*65 + 64 */
#define NDG   (NDEMO * BATCH)   /* 4096 demo groups */
#define NGRP  (NDG + BATCH)     /* 4352 total groups */
#define GPB   4                 /* groups per block */
#define NBLK  (NGRP / GPB)      /* 1088 blocks */

typedef __bf16 bf16x8 __attribute__((ext_vector_type(8)));
typedef float  f32x4  __attribute__((ext_vector_type(4)));

// f32 -> bf16 round-to-nearest-even, packed pair
static __device__ __forceinline__ unsigned pack_bf16x2(float a, float b) {
    unsigned ua = __float_as_uint(a);
    unsigned ub = __float_as_uint(b);
    unsigned ra = (ua + 0x7FFFu + ((ua >> 16) & 1u)) >> 16;
    unsigned rb = (ub + 0x7FFFu + ((ub >> 16) & 1u)) >> 16;
    return (ra & 0xFFFFu) | (rb << 16);
}

static __device__ __forceinline__ uint16_t f32_to_bf16_bits(float a) {
    unsigned ua = __float_as_uint(a);
    return (uint16_t)((ua + 0x7FFFu + ((ua >> 16) & 1u)) >> 16);
}

// ---------------------------------------------------------------------------
// Prologue: W_obj (f32, [k=256][t=256]) -> Wt (bf16 bits, [t=256][k=256])
// ---------------------------------------------------------------------------
__global__ void wconv_kernel(const float* __restrict__ W, uint16_t* __restrict__ Wt) {
    int n = blockIdx.x;
    int k = threadIdx.x;
    Wt[n * TOK + k] = f32_to_bf16_bits(W[k * TOK + n]);
}

// ---------------------------------------------------------------------------
// Fused main kernel. 1088 blocks x 512 threads; block i handles groups
// 4i..4i+3 (contiguous in memory) with a 2-deep register prefetch pipeline.
// Demo blocks also emit their action rows; blocks 0..63 emit the instr rows.
// ---------------------------------------------------------------------------
__global__ __launch_bounds__(512, 4) void obj_fused_kernel(
    const float* __restrict__ demo_obj,   // (16,256,64,256)
    const float* __restrict__ cur,        // (256,64,256)
    const float* __restrict__ b_obj,      // (256,)
    const __bf16* __restrict__ Wt,        // (256 tok, 256 k) bf16
    const float* __restrict__ demo_act,   // (16,256,7)
    const float* __restrict__ W_act,      // (7,256)
    const float* __restrict__ b_act,      // (256,)
    const float* __restrict__ instr,      // (256,768)
    const float* __restrict__ W_instr,    // (768,256)
    const float* __restrict__ b_instr,    // (256,)
    float* __restrict__ out)              // (256,1105,256)
{
    int blk = blockIdx.x;
    int t = threadIdx.x;

    // 64 rows x 256 bf16 (512 B/row), XOR-swizzled: byte ^= (row&7)<<4
    __shared__ __align__(16) unsigned char lds[64 * 512];

    int g0 = blk * GPB;
    bool demo = (g0 < NDG);   // block-uniform: blocks are purely demo or purely cur

    // ---- prologue: issue prefetch for first group ----
    float4 pre[8];
    {
        const float* s0 = demo ? demo_obj + (size_t)g0 * (NOBJ * TOK)
                               : cur + (size_t)(g0 - NDG) * (NOBJ * TOK);
#pragma unroll
        for (int c = 0; c < 4; ++c) {
            const float4* p = reinterpret_cast<const float4*>(s0 + (size_t)(c * 512 + t) * 8);
            pre[2 * c]     = p[0];
            pre[2 * c + 1] = p[1];
        }
    }

    int wave = t >> 6, lane = t & 63;
    int l15 = lane & 15, l4 = lane >> 4;
    int wr = wave >> 2;    // 0..1 : 32-row group
    int wc = wave & 3;     // 0..3 : 64-col group
    int n0 = wc * 64;

    float bv[4];
#pragma unroll
    for (int j = 0; j < 4; ++j) bv[j] = b_obj[n0 + j * 16 + l15];

#pragma unroll 1
    for (int it = 0; it < GPB; ++it) {
        int g = g0 + it;

        __syncthreads();   // LDS free (previous group's compute done)

        // ---- convert + write staged group to LDS ----
#pragma unroll
        for (int c = 0; c < 4; ++c) {
            int chunk = c * 512 + t;       // 2048 chunks of 16B
            int row = chunk >> 5;
            int kc  = chunk & 31;
            uint4 w;
            w.x = pack_bf16x2(pre[2 * c].x,     pre[2 * c].y);
            w.y = pack_bf16x2(pre[2 * c].z,     pre[2 * c].w);
            w.z = pack_bf16x2(pre[2 * c + 1].x, pre[2 * c + 1].y);
            w.w = pack_bf16x2(pre[2 * c + 1].z, pre[2 * c + 1].w);
            unsigned off = (unsigned)(row * 512 + kc * 16) ^ (unsigned)((row & 7) << 4);
            *reinterpret_cast<uint4*>(lds + off) = w;
        }

        // ---- issue prefetch for next group (overlaps compute+store below) ----
        if (it + 1 < GPB) {
            int gn = g + 1;
            const float* sn = demo ? demo_obj + (size_t)gn * (NOBJ * TOK)
                                   : cur + (size_t)(gn - NDG) * (NOBJ * TOK);
#pragma unroll
            for (int c = 0; c < 4; ++c) {
                const float4* p = reinterpret_cast<const float4*>(sn + (size_t)(c * 512 + t) * 8);
                pre[2 * c]     = p[0];
                pre[2 * c + 1] = p[1];
            }
        }

        __syncthreads();   // LDS ready

        // ---- MFMA compute: this wave's 32x64 tile ----
        f32x4 acc[2][4];
#pragma unroll
        for (int i = 0; i < 2; ++i)
#pragma unroll
            for (int j = 0; j < 4; ++j) {
                f32x4 z = {0.0f, 0.0f, 0.0f, 0.0f};
                acc[i][j] = z;
            }

#pragma unroll 1
        for (int s = 0; s < 8; ++s) {
            bf16x8 a[2];
#pragma unroll
            for (int i = 0; i < 2; ++i) {
                int row = wr * 32 + i * 16 + l15;
                unsigned off = (unsigned)(row * 512 + (s * 4 + l4) * 16) ^ (unsigned)((row & 7) << 4);
                a[i] = *reinterpret_cast<const bf16x8*>(lds + off);
            }
#pragma unroll
            for (int j = 0; j < 4; ++j) {
                bf16x8 bfj = *reinterpret_cast<const bf16x8*>(
                    Wt + (size_t)(n0 + j * 16 + l15) * TOK + s * 32 + l4 * 8);
#pragma unroll
                for (int i = 0; i < 2; ++i)
                    acc[i][j] = __builtin_amdgcn_mfma_f32_16x16x32_bf16(a[i], bfj, acc[i][j], 0, 0, 0);
            }
        }

        // ---- epilogue: bias + store ----
        int row_base;
        if (demo) {
            int d = g >> 8, b = g & 255;
            row_base = b * SEQ + 1 + d * (NOBJ + 1);
        } else {
            int b = g - NDG;
            row_base = b * SEQ + 1 + NDEMO * (NOBJ + 1);
        }

#pragma unroll
        for (int i = 0; i < 2; ++i)
#pragma unroll
            for (int j = 0; j < 4; ++j) {
                int col = n0 + j * 16 + l15;
#pragma unroll
                for (int r = 0; r < 4; ++r) {
                    int row = row_base + wr * 32 + i * 16 + l4 * 4 + r;
                    out[(size_t)row * TOK + col] = acc[i][j][r] + bv[j];
                }
            }

        // ---- fused action row (demo groups only) ----
        if (demo && t < TOK) {
            int d = g >> 8, b = g & 255;
            const float* a = demo_act + (size_t)(d * BATCH + b) * 7;
            float v = b_act[t];
#pragma unroll
            for (int k = 0; k < 7; ++k) v += a[k] * W_act[k * TOK + t];
            out[(size_t)(b * SEQ + (d + 1) * (NOBJ + 1)) * TOK + t] = v;
        }
    }

    // ---- fused instr rows: blocks 0..63 each produce 4 rows of (B,0,:) ----
    if (blk < 64) {
        int b0 = blk * 4;
        int col  = t & 255;
        int rsel = t >> 8;                  // 0..1 (wave-uniform)
        int r0 = b0 + rsel, r1 = b0 + rsel + 2;
        const float* i0 = instr + (size_t)r0 * 768;
        const float* i1 = instr + (size_t)r1 * 768;
        float a0 = b_instr[col], a1 = a0;
#pragma unroll 4
        for (int k = 0; k < 768; ++k) {
            float wv = W_instr[(size_t)k * TOK + col];
            a0 += i0[k] * wv;
            a1 += i1[k] * wv;
        }
        out[(size_t)r0 * SEQ * TOK + col] = a0;
        out[(size_t)r1 * SEQ * TOK + col] = a1;
    }
}

extern "C" void kernel_launch(void* const* d_in, const int* in_sizes, int n_in,
                              void* d_out, int out_size, void* d_ws, size_t ws_size,
                              hipStream_t stream) {
    (void)in_sizes; (void)n_in; (void)out_size; (void)ws_size;
    const float* instr    = (const float*)d_in[0];
    const float* demo_obj = (const float*)d_in[1];
    const float* demo_act = (const float*)d_in[2];
    const float* cur      = (const float*)d_in[3];
    const float* W_instr  = (const float*)d_in[4];
    const float* b_instr  = (const float*)d_in[5];
    const float* W_act    = (const float*)d_in[6];
    const float* b_act    = (const float*)d_in[7];
    const float* W_obj    = (const float*)d_in[8];
    const float* b_obj    = (const float*)d_in[9];
    float* out = (float*)d_out;

    uint16_t* Wt = (uint16_t*)d_ws;   // 256*256 bf16 = 128 KB

    wconv_kernel<<<256, 256, 0, stream>>>(W_obj, Wt);
    obj_fused_kernel<<<NBLK, 512, 0, stream>>>(
        demo_obj, cur, b_obj, (const __bf16*)d_ws,
        demo_act, W_act, b_act, instr, W_instr, b_instr, out);
}